// Round 5
// baseline (357.475 us; speedup 1.0000x reference)
//
#include <hip/hip_runtime.h>
#include <math.h>

#define N_TOK 131072
#define N_E   1024
#define E_DIM 64
#define BETA  0.4

// d_out layout (float32, concatenated in return order):
#define ZQ_OFF   0
#define LOSS_OFF 8388608
#define IDX_OFF  8388609
#define PERP_OFF 8519681

// d_ws usage: 256 doubles (per-block sum_sq partials). Nothing needs init.
typedef _Float16 f16x8 __attribute__((ext_vector_type(8)));
typedef float f32x4  __attribute__((ext_vector_type(4)));
typedef unsigned long long u64;

__device__ __forceinline__ unsigned med3u(unsigned a, unsigned b, unsigned c) {
    unsigned d;
    asm("v_med3_u32 %0, %1, %2, %3" : "=v"(d) : "v"(a), "v"(b), "v"(c));
    return d;
}

// ONE persistent kernel: 256 blocks x 1024 threads (1 block/CU, 16 waves).
// Per block: frag codebook->LDS fp16 (x1024 scale), c2h in-block, fp16 MFMA
// screen sweep (R4-validated), top-3 route (settled / 2-cand / full) into LDS
// lists, settled epilogue, then in-block exact fixups. No global worklists,
// no global counts, no init kernels. d_ws: per-block sum_sq slot only.
__global__ __launch_bounds__(1024, 4) void vq_all(
    const float* __restrict__ z, const float* __restrict__ cb,
    double* __restrict__ slots, float margin_u, float* __restrict__ out) {

    __shared__ __align__(16) unsigned char sbuf[131072];  // fp16 codebook frags
    __shared__ __align__(8)  unsigned short c2s[N_E];     // fp16(-512*c2)
    __shared__ int   best_s[512];
    __shared__ unsigned char flag_s[512];
    __shared__ unsigned listA[512];        // (tl<<20)|(e1<<10)|e2
    __shared__ unsigned short listB[512];  // tl
    __shared__ int cntA, cntB;
    __shared__ double wred[16], dredA[16], dredB[16];

    const int tid  = threadIdx.x;
    const int lane = tid & 63;
    const int wid  = tid >> 6;
    const int col  = lane & 15;
    const int quad = lane >> 4;
    const int blk_tok0 = blockIdx.x * 512;
    const int wave_tok0 = blk_tok0 + wid * 32;

    if (tid == 0) { cntA = 0; cntB = 0; }

    // z fragment loads first (HBM latency overlaps frag/c2 phases)
    float4 zl[2][4];
#pragma unroll
    for (int m = 0; m < 2; ++m) {
        const float* zr = z + (size_t)(wave_tok0 + m * 16 + col) * E_DIM + quad * 8;
#pragma unroll
        for (int kc = 0; kc < 2; ++kc) {
            zl[m][kc * 2]     = *(const float4*)(zr + kc * 32);
            zl[m][kc * 2 + 1] = *(const float4*)(zr + kc * 32 + 4);
        }
    }

    // per-block frag: thread t builds fh elements [64t, 64t+64) directly in
    // LDS (identical math to the old frag_kernel -> identical fp16 values).
    // li permuted by lane to spread ds_write banks (32-way -> 8-way).
    {
        const int cc = tid >> 3;
        const int l0 = (tid & 7) * 8;
#pragma unroll
        for (int li0 = 0; li0 < 8; ++li0) {
            const int li = (li0 + lane) & 7;
            const int l = l0 + li;
            const int code = (cc >> 1) * 16 + (l & 15);
            const int k0 = (cc & 1) * 32 + (l >> 4) * 8;
            const float4* p = (const float4*)(cb + (size_t)code * E_DIM + k0);
            float4 u0 = p[0], u1 = p[1];
            union { _Float16 h[8]; uint4 u; } pk;
            pk.h[0] = (_Float16)(u0.x * 1024.0f);
            pk.h[1] = (_Float16)(u0.y * 1024.0f);
            pk.h[2] = (_Float16)(u0.z * 1024.0f);
            pk.h[3] = (_Float16)(u0.w * 1024.0f);
            pk.h[4] = (_Float16)(u1.x * 1024.0f);
            pk.h[5] = (_Float16)(u1.y * 1024.0f);
            pk.h[6] = (_Float16)(u1.z * 1024.0f);
            pk.h[7] = (_Float16)(u1.w * 1024.0f);
            *(uint4*)(sbuf + tid * 128 + li * 16) = pk.u;
        }
    }
    // c2h: thread = code; RN32(exact f64 ||c||^2), same op order everywhere.
    {
        const float* p = cb + (size_t)tid * E_DIM;
        double s = 0.0;
#pragma unroll
        for (int k = 0; k < E_DIM; ++k) {
            double c = (double)p[k];
            s = fma(c, c, s);
        }
        union { _Float16 h; unsigned short u; } q;
        q.h = (_Float16)(-512.0f * (float)s);
        c2s[tid] = q.u;
    }

    // A fragments
    f16x8 Ah[2][2];
#pragma unroll
    for (int m = 0; m < 2; ++m)
#pragma unroll
        for (int kc = 0; kc < 2; ++kc) {
            float4 u0 = zl[m][kc * 2], u1 = zl[m][kc * 2 + 1];
            f16x8 a;
            a[0] = (_Float16)u0.x; a[1] = (_Float16)u0.y;
            a[2] = (_Float16)u0.z; a[3] = (_Float16)u0.w;
            a[4] = (_Float16)u1.x; a[5] = (_Float16)u1.y;
            a[6] = (_Float16)u1.z; a[7] = (_Float16)u1.w;
            Ah[m][kc] = a;
        }

    // top-3 packed-key MAX tracker
    unsigned k1[2][4], k2[2][4], k3[2][4];
#pragma unroll
    for (int m = 0; m < 2; ++m)
#pragma unroll
        for (int r = 0; r < 4; ++r) { k1[m][r] = 0u; k2[m][r] = 0u; k3[m][r] = 0u; }

    __syncthreads();   // frag + c2 complete

    // sweep: u'' = 1024*dot - 512*c2 + 64 > 0; key = (bits&~63)|(63-cl)
#pragma unroll 4
    for (int cl = 0; cl < 64; ++cl) {
        const unsigned char* bp = sbuf + cl * 2048 + lane * 16;
        union { uint4 u; f16x8 v; } b0, b1;
        b0.u = *(const uint4*)(bp);
        b1.u = *(const uint4*)(bp + 1024);
        union { unsigned short us; _Float16 h; } cv;
        cv.us = c2s[cl * 16 + col];
        const float ch = 64.0f + (float)cv.h;
        const f32x4 cinit = {ch, ch, ch, ch};
        const unsigned ctag = (unsigned)(63 - cl);
#pragma unroll
        for (int m = 0; m < 2; ++m) {
            f32x4 acc = __builtin_amdgcn_mfma_f32_16x16x32_f16(
                Ah[m][0], b0.v, cinit, 0, 0, 0);
            acc = __builtin_amdgcn_mfma_f32_16x16x32_f16(
                Ah[m][1], b1.v, acc, 0, 0, 0);
#pragma unroll
            for (int r = 0; r < 4; ++r) {
                unsigned key = (__float_as_uint(acc[r]) & 0xFFFFFFC0u) | ctag;
                unsigned t1 = min(k1[m][r], key);
                k3[m][r] = med3u(k2[m][r], k3[m][r], t1);
                k2[m][r] = med3u(k1[m][r], k2[m][r], key);
                k1[m][r] = max(k1[m][r], key);
            }
        }
    }

    // merge + route into LDS lists
#pragma unroll 1
    for (int m = 0; m < 2; ++m) {
#pragma unroll 1
        for (int r = 0; r < 4; ++r) {
            const unsigned l1 = k1[m][r], l2 = k2[m][r], l3 = k3[m][r];
            unsigned g1 = l1, g2 = l2, g3 = l3;
#pragma unroll
            for (int d = 1; d < 16; d <<= 1) {
                unsigned p1 = __shfl_xor(g1, d, 64);
                unsigned p2 = __shfl_xor(g2, d, 64);
                unsigned p3 = __shfl_xor(g3, d, 64);
                unsigned t1 = min(g1, p1);
                g3 = med3u(g2, g3, t1);
                g2 = med3u(g1, g2, p1);
                g1 = max(g1, p1);
                g3 = med3u(g2, g3, p2);
                g2 = max(g2, p2);
                g3 = med3u(g2, g3, p3);
            }
            u64 bal1 = __ballot((l1 == g1) || (l2 == g1) || (l3 == g1));
            u64 bal2 = __ballot((l1 == g2) || (l2 == g2) || (l3 == g2));
            if (col == 0) {
                const int tl = wid * 32 + m * 16 + quad * 4 + r;
                unsigned m1 = (unsigned)((bal1 >> (quad * 16)) & 0xFFFFu);
                int c1 = __ffs(m1) - 1;
                int bbest = (63 - (int)(g1 & 63u)) * 16 + c1;
                float v1 = __uint_as_float(g1 & 0xFFFFFFC0u);
                float v2 = __uint_as_float(g2 & 0xFFFFFFC0u);
                float v3 = __uint_as_float(g3 & 0xFFFFFFC0u);
                int typ = 0, bsec = 0;
                if (v1 - v2 < margin_u) {
                    if (v1 - v3 < margin_u) typ = 2;
                    else {
                        unsigned m2 = (unsigned)((bal2 >> (quad * 16)) & 0xFFFFu);
                        if (g2 == g1) m2 &= ~(1u << c1);
                        if (__popc(m2) == 1) {
                            bsec = (63 - (int)(g2 & 63u)) * 16 + (__ffs(m2) - 1);
                            typ = 1;
                        } else typ = 2;
                    }
                }
                best_s[tl] = bbest;
                flag_s[tl] = typ ? 1 : 0;
                if (typ == 1) {
                    int pos = atomicAdd(&cntA, 1);
                    listA[pos] = ((unsigned)tl << 20) |
                                 ((unsigned)bbest << 10) | (unsigned)bsec;
                } else if (typ == 2) {
                    int pos = atomicAdd(&cntB, 1);
                    listB[pos] = (unsigned short)tl;
                }
            }
        }
    }

    // settled epilogue: coalesced z_q / loss partials (own-wave tokens only)
    {
        const int sub = lane & 15, grp = lane >> 4;
        double dl = 0.0;
        const float4* zrow = (const float4*)z;
        const float4* crow = (const float4*)cb;
        float4* qrow = (float4*)(out + ZQ_OFF);
#pragma unroll
        for (int p = 0; p < 8; ++p) {
            int tl = wid * 32 + p * 4 + grp;
            if (!flag_s[tl]) {
                int n = blk_tok0 + tl;
                float4 z4 = zrow[(size_t)n * 16 + sub];
                float4 c4 = crow[(size_t)best_s[tl] * 16 + sub];
                float dx = c4.x - z4.x, dy = c4.y - z4.y;
                float dz = c4.z - z4.z, dw = c4.w - z4.w;
                float4 q;
                q.x = z4.x + dx; q.y = z4.y + dy;
                q.z = z4.z + dz; q.w = z4.w + dw;
                qrow[(size_t)n * 16 + sub] = q;
                dl += (double)dx * dx + (double)dy * dy
                    + (double)dz * dz + (double)dw * dw;
            }
        }
#pragma unroll
        for (int off = 32; off > 0; off >>= 1)
            dl += __shfl_down(dl, off, 64);
        if (lane == 0) wred[wid] = dl;
    }

    __syncthreads();   // lists complete; sbuf free for reuse

    // ---- fix-B: full scan, one token per wave, 16 codes per lane ----
    float* zsc = (float*)(sbuf + 8192);   // 16 waves x 64 f32 scratch
    {
        const int nB = cntB;
        double db = 0.0;
        for (int ei = wid; ei < nB; ei += 16) {
            const int tl = listB[ei];
            const int n  = blk_tok0 + tl;
            zsc[wid * 64 + lane] = z[(size_t)n * E_DIM + lane];
            const float* zr = zsc + wid * 64;
            // numpy-pairwise z2 (exact f32 copies)
            float r8[8];
#pragma unroll
            for (int j = 0; j < 8; ++j) r8[j] = __fmul_rn(zr[j], zr[j]);
#pragma unroll
            for (int i = 8; i < 64; i += 8)
#pragma unroll
                for (int j = 0; j < 8; ++j)
                    r8[j] = __fadd_rn(r8[j], __fmul_rn(zr[i + j], zr[i + j]));
            const float z2 = __fadd_rn(
                __fadd_rn(__fadd_rn(r8[0], r8[1]), __fadd_rn(r8[2], r8[3])),
                __fadd_rn(__fadd_rn(r8[4], r8[5]), __fadd_rn(r8[6], r8[7])));
            // f32 prescreen of codes lane+64s
            float d16[16];
            float dml = 1e30f;
#pragma unroll
            for (int s = 0; s < 16; ++s) {
                const int e = s * 64 + lane;
                const float4* cp4 = (const float4*)(cb + (size_t)e * E_DIM);
                float a0 = 0.f, a1 = 0.f, a2 = 0.f, a3 = 0.f;
#pragma unroll
                for (int k4 = 0; k4 < 16; ++k4) {
                    float4 c4 = cp4[k4];
                    a0 = fmaf(zr[k4 * 4],     c4.x, a0);
                    a1 = fmaf(zr[k4 * 4 + 1], c4.y, a1);
                    a2 = fmaf(zr[k4 * 4 + 2], c4.z, a2);
                    a3 = fmaf(zr[k4 * 4 + 3], c4.w, a3);
                }
                union { unsigned short u; _Float16 h; } cv; cv.u = c2s[e];
                float c2a = (float)cv.h * (-1.0f / 512.0f);
                float d = z2 + c2a - 2.0f * ((a0 + a1) + (a2 + a3));
                d16[s] = d;
                dml = fminf(dml, d);
            }
#pragma unroll
            for (int d = 1; d < 64; d <<= 1)
                dml = fminf(dml, __shfl_xor(dml, d, 64));
            const float thr = dml + 4e-3f;   // >> 2x prescreen error (validated)
            u64 bk = ~0ull;
#pragma unroll
            for (int s = 0; s < 16; ++s) {
                if (d16[s] <= thr) {
                    const int e = s * 64 + lane;
                    const float* cp = cb + (size_t)e * E_DIM;
                    double cs = 0.0, mm = 0.0;
#pragma unroll
                    for (int k = 0; k < E_DIM; ++k) {
                        double c = (double)cp[k];
                        cs = fma(c, c, cs);
                        mm = fma((double)zr[k], c, mm);
                    }
                    float d = __fsub_rn(__fadd_rn(z2, (float)cs),
                                        __fmul_rn(2.0f, (float)mm));
                    u64 key = ((u64)__float_as_uint(d) << 32) | (unsigned)e;
                    if (key < bk) bk = key;
                }
            }
#pragma unroll
            for (int d = 1; d < 64; d <<= 1) {
                u64 o = __shfl_xor(bk, d, 64);
                if (o < bk) bk = o;
            }
            const int best = (int)(bk & 0xffffffffull);
            float cv2 = cb[(size_t)best * E_DIM + lane];
            float zi = zr[lane];
            float diff = cv2 - zi;
            out[ZQ_OFF + (size_t)n * E_DIM + lane] = zi + diff;
            double d2 = (double)diff * (double)diff;
#pragma unroll
            for (int off = 32; off > 0; off >>= 1)
                d2 += __shfl_down(d2, off, 64);
            if (lane == 0) { db += d2; best_s[tl] = best; }
        }
        if (lane == 0) dredB[wid] = db;
    }

    // ---- fix-A: 2-candidate exact, one thread per entry ----
    {
        const int nA = cntA;
        double da = 0.0;
        for (int t = tid; t < nA; t += 1024) {
            const unsigned ent = listA[t];
            const int tl = (int)(ent >> 20);
            const int e1 = (int)((ent >> 10) & 1023u);
            const int e2 = (int)(ent & 1023u);
            const int n  = blk_tok0 + tl;
            const float* zrow = z + (size_t)n * E_DIM;
            float r8[8];
#pragma unroll
            for (int j = 0; j < 8; ++j) r8[j] = __fmul_rn(zrow[j], zrow[j]);
#pragma unroll
            for (int i = 8; i < 64; i += 8)
#pragma unroll
                for (int j = 0; j < 8; ++j)
                    r8[j] = __fadd_rn(r8[j], __fmul_rn(zrow[i + j], zrow[i + j]));
            float z2 = __fadd_rn(
                __fadd_rn(__fadd_rn(r8[0], r8[1]), __fadd_rn(r8[2], r8[3])),
                __fadd_rn(__fadd_rn(r8[4], r8[5]), __fadd_rn(r8[6], r8[7])));
            u64 bk = ~0ull;
#pragma unroll
            for (int c = 0; c < 2; ++c) {
                const int e = c ? e2 : e1;
                const float* cp = cb + (size_t)e * E_DIM;
                double cs = 0.0, mm = 0.0;
#pragma unroll
                for (int k = 0; k < E_DIM; ++k) {
                    double cc = (double)cp[k];
                    cs = fma(cc, cc, cs);
                    mm = fma((double)zrow[k], cc, mm);
                }
                float d = __fsub_rn(__fadd_rn(z2, (float)cs),
                                    __fmul_rn(2.0f, (float)mm));
                u64 key = ((u64)__float_as_uint(d) << 32) | (unsigned)e;
                if (key < bk) bk = key;
            }
            const int best = (int)(bk & 0xffffffffull);
            const float4* cp4 = (const float4*)(cb + (size_t)best * E_DIM);
            const float4* zp4 = (const float4*)zrow;
            float4* qp = (float4*)(out + ZQ_OFF + (size_t)n * E_DIM);
            double dd = 0.0;
#pragma unroll
            for (int k = 0; k < 16; ++k) {
                float4 c4 = cp4[k]; float4 z4 = zp4[k];
                float dx = c4.x - z4.x, dy = c4.y - z4.y;
                float dz = c4.z - z4.z, dw = c4.w - z4.w;
                float4 q;
                q.x = z4.x + dx; q.y = z4.y + dy;
                q.z = z4.z + dz; q.w = z4.w + dw;
                qp[k] = q;
                dd += (double)dx * dx + (double)dy * dy
                    + (double)dz * dz + (double)dw * dw;
            }
            best_s[tl] = best;
            da += dd;
        }
#pragma unroll
        for (int off = 32; off > 0; off >>= 1)
            da += __shfl_down(da, off, 64);
        if (lane == 0) dredA[wid] = da;
    }

    __syncthreads();

    // unified coalesced idx write + per-block sum_sq slot (non-atomic)
    if (tid < 512)
        out[IDX_OFF + blk_tok0 + tid] = (float)best_s[tid];
    if (tid == 0) {
        double s = 0.0;
#pragma unroll
        for (int i = 0; i < 16; ++i) s += wred[i] + dredA[i] + dredB[i];
        slots[blockIdx.x] = s;
    }
}

// Single-block finalize: histogram straight from the idx array (no global
// counts, no init), entropy, mse from the 256 per-block slots.
__global__ __launch_bounds__(1024) void finalize2(
    const double* __restrict__ slots, float* __restrict__ out) {
    __shared__ int hist[N_E];
    __shared__ double red[1024];
    const int tid = threadIdx.x;
    hist[tid] = 0;
    __syncthreads();
    const float4* idx4 = (const float4*)(out + IDX_OFF);
    for (int i = tid; i < N_TOK / 4; i += 1024) {
        float4 v = idx4[i];
        atomicAdd(&hist[(int)v.x], 1);
        atomicAdd(&hist[(int)v.y], 1);
        atomicAdd(&hist[(int)v.z], 1);
        atomicAdd(&hist[(int)v.w], 1);
    }
    __syncthreads();
    double em = (double)hist[tid] / (double)N_TOK;
    red[tid] = -em * log(em + 1e-10);
    __syncthreads();
    for (int s = 512; s > 0; s >>= 1) {
        if (tid < s) red[tid] += red[tid + s];
        __syncthreads();
    }
    if (tid == 0) {
        double usage = red[0];
        double ss = 0.0;
        for (int i = 0; i < 256; ++i) ss += slots[i];
        double mse = ss / (double)((size_t)N_TOK * E_DIM);
        out[LOSS_OFF] = (float)((1.0 + BETA) * mse + 0.01 * usage);
        out[PERP_OFF] = (float)exp(usage);
    }
}

extern "C" void kernel_launch(void* const* d_in, const int* in_sizes, int n_in,
                              void* d_out, int out_size, void* d_ws, size_t ws_size,
                              hipStream_t stream) {
    const float* z  = (const float*)d_in[0];
    const float* cb = (const float*)d_in[1];
    float* out = (float*)d_out;
    double* slots = (double*)d_ws;   // 256 doubles

    // u''-space margin 0.071 validated rounds 1-4 (absmax 0 throughout).
    vq_all<<<256, 1024, 0, stream>>>(z, cb, slots, 0.071f, out);
    finalize2<<<1, 1024, 0, stream>>>(slots, out);
}